// Round 9
// baseline (279.764 us; speedup 1.0000x reference)
//
#include <hip/hip_runtime.h>

#define NROWS 16384
#define DDIM 64
#define KCB 8192
#define CIN 512
#define OUTC 512
#define OUT_MAIN 8388608

typedef float f4 __attribute__((ext_vector_type(4)));
typedef float f32x16 __attribute__((ext_vector_type(16)));
typedef __bf16 bf16x4 __attribute__((ext_vector_type(4)));
typedef __bf16 bf16x8 __attribute__((ext_vector_type(8)));

// d_out scratch layout (f32 units). k_dec overwrites [0, OUT_MAIN) last.
#define OFF_ZBF 0         // zbf: 3*4*512*64*8 = 3,145,728 bf16 = 1,572,864 f32
#define OFF_EBF 1572864   // ebf: 3*4*256*64*8 = 1,572,864 bf16 = 786,432 f32
#define OFF_E2H 2359296   // e2h[8192] = 0.5*||e||^2
#define OFF_PMV 2367488   // pmv[16][16384] (score partial max)
#define OFF_PMI 2629632   // pmi[16][16384] (int)
#define ZS_STRIDE 1048576  // bf16 elems per z split level (4*512*64*8)
#define ES_STRIDE 524288   // bf16 elems per e split level (4*256*64*8)

// ---------------- K1: encoder 1x1 conv, LDS-free scalar-broadcast GEMV.
// 256 blocks x 512 threads (8 waves). Lane l -> token n = bid*64 + l;
// wave wv (uniform via readfirstlane) -> d-octet d = wv*8 + j.
// Weights w_in[d][c] are wave-uniform -> scalar loads (SGPR), FMA v,s,v.
// Epilogue: 3-split bf16 written directly in zbf MFMA-frag layout
// (thread's d-octet == one fragment's j=0..7).
__global__ __launch_bounds__(512) void k_enc(const float* __restrict__ x,
                                             const float* __restrict__ w_in,
                                             const float* __restrict__ b_in,
                                             __bf16* __restrict__ zbf) {
  const int t = threadIdx.x;
  const int l = t & 63;
  const int wv = __builtin_amdgcn_readfirstlane(t >> 6);  // 0..7, uniform
  const int n = blockIdx.x * 64 + l;
  const int b = n >> 10, hw = n & 1023;
  const float* xp = x + ((size_t)b * CIN) * 1024 + hw;
  const float* wrow = w_in + (size_t)(wv * 8) * CIN;  // uniform

  float acc[8];
#pragma unroll
  for (int j = 0; j < 8; ++j) acc[j] = 0.f;

#pragma unroll 1
  for (int c0 = 0; c0 < CIN; c0 += 16) {
    float xv[16];
#pragma unroll
    for (int cc = 0; cc < 16; ++cc) xv[cc] = xp[(size_t)(c0 + cc) * 1024];
#pragma unroll
    for (int cc = 0; cc < 16; ++cc) {
#pragma unroll
      for (int j = 0; j < 8; ++j)
        acc[j] = fmaf(xv[cc], wrow[j * CIN + c0 + cc], acc[j]);
    }
  }
#pragma unroll
  for (int j = 0; j < 8; ++j) acc[j] += b_in[wv * 8 + j];

  // split epilogue: d = wv*8 + j = kb*16 + khalf*8 + j
  const int kb = wv >> 1, khalf = wv & 1;
  const int g = n >> 5, row = n & 31;
  bf16x8 s0, s1, s2;
#pragma unroll
  for (int j = 0; j < 8; ++j) {
    float v = acc[j];
    __bf16 a0 = (__bf16)v;
    float r1 = v - (float)a0;
    __bf16 a1 = (__bf16)r1;
    float r2 = r1 - (float)a1;
    s0[j] = a0; s1[j] = a1; s2[j] = (__bf16)r2;
  }
  const size_t base = ((size_t)(kb * 512 + g) * 64 + khalf * 32 + row) * 8;
  *(bf16x8*)(zbf + base) = s0;
  *(bf16x8*)(zbf + base + ZS_STRIDE) = s1;
  *(bf16x8*)(zbf + base + 2 * ZS_STRIDE) = s2;
}

// ---------------- K2: emb -> bf16 3-split frag layout + e2h = 0.5*||e||^2
// ebf[s][kb][cg][lane][j]: lane = khalf*32 + (code&31), value = split_s(emb[code][k])
__global__ __launch_bounds__(256) void k_prep(const float* __restrict__ emb,
                                              __bf16* __restrict__ ebf,
                                              float* __restrict__ e2h) {
  __shared__ float s2[4][64];
  const int C0 = blockIdx.x * 64;
  const int t = threadIdx.x;
  const int cl = t & 63, kb = t >> 6;
  const int c = C0 + cl;
  const int cg = blockIdx.x * 2 + (cl >> 5);
  float e[16];
  {
    const f4* ep = (const f4*)(emb + (size_t)c * DDIM + kb * 16);
#pragma unroll
    for (int q = 0; q < 4; ++q) {
      f4 v = ep[q];
      e[q * 4 + 0] = v.x; e[q * 4 + 1] = v.y; e[q * 4 + 2] = v.z; e[q * 4 + 3] = v.w;
    }
  }
  float sq = 0.f;
#pragma unroll
  for (int i = 0; i < 16; ++i) sq = fmaf(e[i], e[i], sq);
  s2[kb][cl] = sq;
  bf16x8 v0[2], v1[2], v2[2];
#pragma unroll
  for (int i = 0; i < 16; ++i) {
    float v = e[i];
    __bf16 a0 = (__bf16)v;
    float r1 = v - (float)a0;
    __bf16 a1 = (__bf16)r1;
    float r2 = r1 - (float)a1;
    v0[i >> 3][i & 7] = a0; v1[i >> 3][i & 7] = a1; v2[i >> 3][i & 7] = (__bf16)r2;
  }
#pragma unroll
  for (int khalf = 0; khalf < 2; ++khalf) {
    const size_t dst = ((size_t)(kb * 256 + cg) * 64 + khalf * 32 + (cl & 31)) * 8;
    *(bf16x8*)(ebf + dst) = v0[khalf];
    *(bf16x8*)(ebf + dst + ES_STRIDE) = v1[khalf];
    *(bf16x8*)(ebf + dst + 2 * ES_STRIDE) = v2[khalf];
  }
  __syncthreads();
  if (t < 64)
    e2h[C0 + t] = 0.5f * (s2[0][t] + s2[1][t] + s2[2][t] + s2[3][t]);
}

// ---------------- K3: split-MFMA distance GEMM + per-lane argmax fold
// 4-wave blocks. Block = 128 rows x 512 codes; wave wv owns rows
// rowblk*128 + wv*32 (zf in registers) and sweeps 16 sts of 32 codes.
// Per st the e-fragments (12 KB) are staged into LDS via global_load_lds
// (double-buffered, 1-barrier pipeline) and shared by all 4 waves.
// C layout: n(row) = lane&31; m(code-offset) = (reg&3)+8*(reg>>2)+4*(lane>>5).
// Within a lane candidates ascend in code, so strict '>' keeps lowest index.
__global__ __launch_bounds__(256, 3) void k_argmin(const __bf16* __restrict__ zbf,
                                                   const __bf16* __restrict__ ebf,
                                                   const float* __restrict__ e2h,
                                                   float* __restrict__ pmv,
                                                   int* __restrict__ pmi) {
  __shared__ __bf16 Als[2][6144];  // [buf][12 frags x 64 lanes x 8]
  const int bid = blockIdx.x;
  const int rowblk = bid >> 4, chunk = bid & 15;
  const int t = threadIdx.x;
  const int l = t & 63;
  const int wv = t >> 6;
  const int h4 = (l >> 5) * 4;
  const int g = rowblk * 4 + wv;  // 32-row group owned by this wave

  // persistent z fragments zf[split][kb] (12 x bf16x8 = 48 VGPR)
  bf16x8 zf[3][4];
#pragma unroll
  for (int s = 0; s < 3; ++s)
#pragma unroll
    for (int kb = 0; kb < 4; ++kb)
      zf[s][kb] = *(const bf16x8*)(zbf + (size_t)s * ZS_STRIDE +
                                   ((size_t)(kb * 512 + g) * 64 + l) * 8);

  float mv = -3.4028235e38f;
  int mi = 0;

  auto stage = [&](int st, int bi) {
    const int cg = chunk * 16 + st;
#pragma unroll
    for (int i = 0; i < 3; ++i) {
      const int fi = wv * 3 + i;  // wave-uniform frag id 0..11
      const int s = fi >> 2, kb = fi & 3;
      const __bf16* src = ebf + (size_t)s * ES_STRIDE +
                          ((size_t)(kb * 256 + cg) * 64 + l) * 8;
      __builtin_amdgcn_global_load_lds(
          (const __attribute__((address_space(1))) void*)src,
          (__attribute__((address_space(3))) void*)&Als[bi][fi * 512 + l * 8],
          16, 0, 0);
    }
  };

  stage(0, 0);
#pragma unroll 1
  for (int st = 0; st < 16; ++st) {
    __syncthreads();  // drains stage(st); all waves done reading buf[st&1 ^ 1]
    if (st + 1 < 16) stage(st + 1, (st + 1) & 1);
    const __bf16* B = &Als[st & 1][0];
    const int cbase = (chunk * 16 + st) * 32;
    f32x16 acc = (f32x16)(0.0f);
    bf16x8 af[4];
#define LDAF(b)                                                              \
  {                                                                          \
    _Pragma("unroll") for (int kb = 0; kb < 4; ++kb) af[kb] =                \
        *(const bf16x8*)(B + ((b)*4 + kb) * 512 + l * 8);                    \
  }
#define SW(a)                                                                \
  {                                                                          \
    _Pragma("unroll") for (int kb = 0; kb < 4; ++kb) acc =                   \
        __builtin_amdgcn_mfma_f32_32x32x16_bf16(af[kb], zf[a][kb], acc, 0,   \
                                                0, 0);                       \
  }
    LDAF(0); SW(0); SW(1); SW(2);
    LDAF(1); SW(0); SW(1);
    LDAF(2); SW(0);
#undef LDAF
#undef SW
    // fold: score = dot - e2/2; strict '>' + ascending order = lowest-tie
    const float* e2p = e2h + cbase + h4;
#pragma unroll
    for (int q = 0; q < 4; ++q) {
      const f4 e2q = *(const f4*)(e2p + q * 8);
#pragma unroll
      for (int i = 0; i < 4; ++i) {
        const float s = acc[q * 4 + i] - e2q[i];
        if (s > mv) { mv = s; mi = cbase + h4 + q * 8 + i; }
      }
    }
  }
  // merge lane l with l^32 (same row, interleaved code sets -> full tie-break)
  {
    float ov = __shfl_xor(mv, 32);
    int oi = __shfl_xor(mi, 32);
    if (ov > mv || (ov == mv && oi < mi)) { mv = ov; mi = oi; }
  }
  if (l < 32) {
    const int row = rowblk * 128 + wv * 32 + l;
    pmv[chunk * NROWS + row] = mv;
    pmi[chunk * NROWS + row] = mi;
  }
}

// ---------------- K4: combine 16 chunk partials (max score; chunks ascend so
// strict '>' keeps the lowest index on ties)
__global__ __launch_bounds__(256) void k_pick(const float* __restrict__ pmv,
                                              const int* __restrict__ pmi,
                                              float* __restrict__ idxf) {
  int n = blockIdx.x * 256 + threadIdx.x;
  float bv = pmv[n];
  int bi = pmi[n];
#pragma unroll
  for (int p = 1; p < 16; ++p) {
    float v = pmv[p * NROWS + n];
    int i = pmi[p * NROWS + n];
    if (v > bv) { bv = v; bi = i; }
  }
  idxf[n] = (float)bi;
}

// ---------------- K5: decoder 1x1 conv, LDS-free scalar-broadcast GEMV.
// 256 blocks x 512 threads. Lane l -> token n = bid*64 + l; wave wv ->
// out-channels [wv*64, wv*64+64) in 8 passes of 8. q = emb[idx[n]] held in
// 16 f4 registers (hoisted out of the pass loop); w_out via wave-uniform
// scalar loads; coalesced stores.
__global__ __launch_bounds__(512) void k_dec(const float* __restrict__ emb,
                                             const float* __restrict__ w_out,
                                             const float* __restrict__ b_out,
                                             const float* __restrict__ idxf,
                                             float* __restrict__ out) {
  const int t = threadIdx.x;
  const int l = t & 63;
  const int wv = __builtin_amdgcn_readfirstlane(t >> 6);  // 0..7, uniform
  const int n = blockIdx.x * 64 + l;
  const int b = n >> 10, hw = n & 1023;
  const int qi = (int)idxf[n];
  const f4* qp = (const f4*)(emb + (size_t)qi * DDIM);
  float* op = out + ((size_t)b * OUTC) * 1024 + hw;

  f4 q[16];
#pragma unroll
  for (int i = 0; i < 16; ++i) q[i] = qp[i];

#pragma unroll 1
  for (int pass = 0; pass < 8; ++pass) {
    const int o0 = wv * 64 + pass * 8;  // uniform
    const float* wr = w_out + (size_t)o0 * DDIM;
    float acc[8];
#pragma unroll
    for (int jo = 0; jo < 8; ++jo) acc[jo] = b_out[o0 + jo];
#pragma unroll
    for (int dc = 0; dc < 8; ++dc) {
      const f4 qa = q[dc * 2];
      const f4 qb = q[dc * 2 + 1];
#pragma unroll
      for (int jo = 0; jo < 8; ++jo) {
        const float* w8 = wr + jo * DDIM + dc * 8;
        acc[jo] = fmaf(qa.x, w8[0], acc[jo]);
        acc[jo] = fmaf(qa.y, w8[1], acc[jo]);
        acc[jo] = fmaf(qa.z, w8[2], acc[jo]);
        acc[jo] = fmaf(qa.w, w8[3], acc[jo]);
        acc[jo] = fmaf(qb.x, w8[4], acc[jo]);
        acc[jo] = fmaf(qb.y, w8[5], acc[jo]);
        acc[jo] = fmaf(qb.z, w8[6], acc[jo]);
        acc[jo] = fmaf(qb.w, w8[7], acc[jo]);
      }
    }
#pragma unroll
    for (int jo = 0; jo < 8; ++jo)
      op[(size_t)(o0 + jo) * 1024] = acc[jo];
  }
}

extern "C" void kernel_launch(void* const* d_in, const int* in_sizes, int n_in,
                              void* d_out, int out_size, void* d_ws, size_t ws_size,
                              hipStream_t stream) {
  const float* x = (const float*)d_in[0];
  const float* w_in = (const float*)d_in[1];
  const float* b_in = (const float*)d_in[2];
  const float* emb = (const float*)d_in[3];
  const float* w_out = (const float*)d_in[4];
  const float* b_out = (const float*)d_in[5];
  float* out = (float*)d_out;

  __bf16* zbf = (__bf16*)(out + OFF_ZBF);
  __bf16* ebf = (__bf16*)(out + OFF_EBF);
  float* e2h = out + OFF_E2H;
  float* pmv = out + OFF_PMV;
  int* pmi = (int*)(out + OFF_PMI);
  float* idxf = out + OUT_MAIN;  // final indices output (as float), d_out tail

  k_enc<<<256, 512, 0, stream>>>(x, w_in, b_in, zbf);
  k_prep<<<128, 256, 0, stream>>>(emb, ebf, e2h);
  k_argmin<<<2048, 256, 0, stream>>>(zbf, ebf, e2h, pmv, pmi);
  k_pick<<<64, 256, 0, stream>>>(pmv, pmi, idxf);
  k_dec<<<256, 512, 0, stream>>>(emb, w_out, b_out, idxf, out);
}